// Round 6
// baseline (468.126 us; speedup 1.0000x reference)
//
#include <hip/hip_runtime.h>
#include <math.h>
#include <stdint.h>

// sLSTM cell, B=16384, D=H=1024.
// bf16-MFMA path (needs ws >= ~114 MB):
//   cvt kernels build: A=[x|h_prev] bf16 [16384][2048], WT gate-interleaved bf16 [4096][2048],
//   WyT bf16 [1024][1024], bsum f32 [4][1024].
//   gemm_gates / gemm_y: 256x256-tile BK=64 MFMA GEMM, mfma_f32_32x32x16_bf16,
//   4 pinned phases per K-tile (m201-style), A dbuf + B triple-buf (160KB LDS),
//   counted vmcnt(4), T2 swizzle, T5 setprio. Fused gate epilogue, chained m-tiles.
// Fallback (small ws): round-1 f32 vector kernels.

typedef __attribute__((ext_vector_type(8))) short bf16x8;
typedef __attribute__((ext_vector_type(4))) float f32x4;
typedef __attribute__((ext_vector_type(16))) float f32x16;

constexpr int Bsz = 16384;
constexpr int Dd  = 1024;
constexpr int Hh  = 1024;
constexpr float EPSv = 1e-7f;

__device__ __forceinline__ unsigned short f2bf(float f) {
    union { float f; uint32_t u; } v; v.f = f;
    uint32_t u = v.u + 0x7fffu + ((v.u >> 16) & 1u);   // RNE
    return (unsigned short)(u >> 16);
}

__device__ __forceinline__ void gload16(const void* g, void* l) {
    __builtin_amdgcn_global_load_lds(
        (const __attribute__((address_space(1))) void*)g,
        (__attribute__((address_space(3))) void*)l, 16, 0, 0);
}

__device__ __forceinline__ float sigm_f(float x) { return 1.f / (1.f + __expf(-x)); }
__device__ __forceinline__ float tanh_f(float x) {   // overflow-safe fast tanh
    const float ax = fabsf(x);
    const float t = __expf(-2.f * ax);
    const float r = (1.f - t) / (1.f + t);
    return copysignf(r, x);
}

// ---------------- conversion kernels ----------------

__global__ __launch_bounds__(256)
void cvt_A(const float* __restrict__ x, const float* __restrict__ hp, unsigned short* __restrict__ A)
{
    const int idx = blockIdx.x * 256 + threadIdx.x;   // 8 elements each
    const int n = idx * 8;
    const int b = n >> 11, k = n & 2047;
    const float* s = (k < 1024) ? (x + (size_t)b * 1024 + k)
                                : (hp + (size_t)b * 1024 + (k - 1024));
    const float4 v0 = *(const float4*)s;
    const float4 v1 = *(const float4*)(s + 4);
    union { unsigned short u[8]; uint4 v; } pk;
    pk.u[0] = f2bf(v0.x); pk.u[1] = f2bf(v0.y); pk.u[2] = f2bf(v0.z); pk.u[3] = f2bf(v0.w);
    pk.u[4] = f2bf(v1.x); pk.u[5] = f2bf(v1.y); pk.u[6] = f2bf(v1.z); pk.u[7] = f2bf(v1.w);
    *(uint4*)(A + n) = pk.v;
}

// src [1024][1024] f32 (rows=k, cols=j) -> dst[c'][kbase+k] bf16.
// mode 0: c' = (j&31)|(g<<5)|((j>>5)<<7)   (gate-interleaved, 32-col granules)
// mode 1: c' = j
__global__ __launch_bounds__(256)
void cvt_T(const float* __restrict__ src, unsigned short* __restrict__ dst,
           int ldd, int kbase, int g, int mode)
{
    __shared__ float tile[64][65];
    const int t = threadIdx.x;
    const int kt = blockIdx.x & 15, jt = blockIdx.x >> 4;
    {
        const int lr = t >> 4, lc = (t & 15) * 4;
        #pragma unroll
        for (int rr = 0; rr < 64; rr += 16) {
            const float4 v = *(const float4*)(src + (size_t)(kt * 64 + rr + lr) * 1024 + jt * 64 + lc);
            tile[rr + lr][lc + 0] = v.x;
            tile[rr + lr][lc + 1] = v.y;
            tile[rr + lr][lc + 2] = v.z;
            tile[rr + lr][lc + 3] = v.w;
        }
    }
    __syncthreads();
    const int jl = t >> 2, kc = (t & 3) * 16;
    const int j = jt * 64 + jl;
    const int cp = mode ? j : ((j & 31) | (g << 5) | ((j >> 5) << 7));
    union { unsigned short u[16]; uint4 v[2]; } pk;
    #pragma unroll
    for (int q = 0; q < 16; ++q) pk.u[q] = f2bf(tile[kc + q][jl]);
    uint4* d = (uint4*)(dst + (size_t)cp * ldd + kbase + kt * 64 + kc);
    d[0] = pk.v[0];
    d[1] = pk.v[1];
}

__global__ __launch_bounds__(256)
void bias_sum(const float* bWz, const float* bRz, const float* bz,
              const float* bWi, const float* bRi, const float* bi,
              const float* bWf, const float* bRf, const float* bf_,
              const float* bWo, const float* bRo, const float* bo,
              float* __restrict__ bs)
{
    const int j = blockIdx.x * 256 + threadIdx.x;   // grid 4
    bs[j]        = bWz[j] + bRz[j] + bz[j];
    bs[1024 + j] = bWi[j] + bRi[j] + bi[j];
    bs[2048 + j] = bWf[j] + bRf[j] + bf_[j];
    bs[3072 + j] = bWo[j] + bRo[j] + bo[j];
}

// ---------------- MFMA GEMM core: 256x256 tile, BK=64, 32x32x16, 4 pinned phases ----------------
// 512 threads = 8 waves (4 wave-rows x 2 wave-cols). Per-wave output 64x128 = 2x4 of 32x32,
// acc[2][4] f32x16. LDS 160KB: Abuf[2] (2x32KB) + Bbuf[3] (3x32KB).
// Swizzle (T2): [row][64k] linear rows; chunk c8 stored at c8^(row&7); staged via
//   inverse-swizzled global source + linear global_load_lds dest (rule #21). 0 conflicts (R3-R5).
// Phases per K-tile (quadrant = k-half x n-half):
//   Ph1(kh0,nh0): rd A(kh0)4+B(nh0,kh0)4 | stgA(f+1,h0) | pin/bar/lgkm0 | 8 MFMA | bar
//   Ph2(kh0,nh1): rd B(nh1,kh0)4         | stgA(f+1,h1) | ...           | 8 MFMA | bar
//   Ph3(kh1,nh0): rd A(kh1)4+B(nh0,kh1)4 | stgB(f+2,h0) | ...           | 8 MFMA | bar
//   Ph4(kh1,nh1): rd B(nh1,kh1)4         | stgB(f+2,h1) | ... | 8 MFMA | vmcnt(4) | bar
// Ledger: tile f reads Abuf[f&1], Bbuf[f%3]; stages A(f+1)->Abuf[f&1^1] (free since f-1.Ph3),
// B(f+2)->Bbuf[(f+2)%3] (free since f-1.Ph4). vmcnt(4) leaves B(f+2) in flight; A(f+1),B(f+1)
// proven landed (B(f+1) staged one full tile earlier). Never vmcnt(0) in loop (T4).

#define PH_PRE() { __builtin_amdgcn_sched_barrier(0); __builtin_amdgcn_s_barrier(); \
    asm volatile("s_waitcnt lgkmcnt(0)" ::: "memory"); __builtin_amdgcn_sched_barrier(0); \
    __builtin_amdgcn_s_setprio(1); }
#define PH_POST() { __builtin_amdgcn_s_setprio(0); __builtin_amdgcn_sched_barrier(0); \
    __builtin_amdgcn_s_barrier(); }
#define MFMA32(d, a, b) d = __builtin_amdgcn_mfma_f32_32x32x16_bf16(a, b, d, 0, 0, 0)

template<int LD, int NTK_LOG2, int NTILES, class Epi>
__device__ void mfma32_chain(const unsigned short* __restrict__ Ag,
                             const unsigned short* __restrict__ Bg,
                             int m0base, int n0, int t,
                             unsigned short* lds, Epi epi)
{
    constexpr int NTK = 1 << NTK_LOG2;
    constexpr int TOT = NTK * NTILES;
    const int lane = t & 63, wid = t >> 6;
    const int wr = wid >> 1, wc = wid & 1;        // 4M x 2N wave grid
    const int l31 = lane & 31, hi5 = lane >> 5, e7 = l31 & 7;
    const int rA0 = wr * 64 + l31;                // A row, mi adds 32
    const int rB0 = wc * 128 + l31;               // B row (c'), nn adds 32
    const int srow = t >> 3;
    const int schk = ((t & 7) ^ (srow & 7)) * 8;  // inverse-swizzled source chunk (shorts)
    const int ldst8 = t * 8;

    f32x16 acc[2][4];
    #pragma unroll
    for (int i = 0; i < 2; ++i)
        #pragma unroll
        for (int j = 0; j < 4; ++j) acc[i][j] = (f32x16)0.f;

    auto stgA = [&](int f, int h, int buf) {
        const int ot = f >> NTK_LOG2, kt = f & (NTK - 1);
        const unsigned short* g = Ag + (size_t)(m0base + ot * 256 + h * 128 + srow) * LD + kt * 64 + schk;
        unsigned short* l = lds + buf * 16384 + h * 8192 + ldst8;
        gload16(g,                 l);
        gload16(g + (size_t)64 * LD, l + 4096);
    };
    auto stgB = [&](int f, int h, int buf) {
        const int kt = f & (NTK - 1);
        const unsigned short* g = Bg + (size_t)(n0 + h * 128 + srow) * LD + kt * 64 + schk;
        unsigned short* l = lds + 32768 + buf * 16384 + h * 8192 + ldst8;
        gload16(g,                 l);
        gload16(g + (size_t)64 * LD, l + 4096);
    };
    auto rdA = [&](int buf, int mi, int ks) {
        return *(const bf16x8*)(lds + buf * 16384 + (rA0 + mi * 32) * 64 + ((((ks << 1) + hi5) ^ e7) << 3));
    };
    auto rdB = [&](int buf, int nn, int ks) {
        return *(const bf16x8*)(lds + 32768 + buf * 16384 + (rB0 + nn * 32) * 64 + ((((ks << 1) + hi5) ^ e7) << 3));
    };

    // prologue: A(0), B(0) -> their buffers; B(1) -> Bbuf1. 12 loads; keep B(1)'s 4 in flight.
    stgA(0, 0, 0); stgA(0, 1, 0);
    stgB(0, 0, 0); stgB(0, 1, 0);
    stgB(1, 0, 1); stgB(1, 1, 1);
    asm volatile("s_waitcnt vmcnt(4)" ::: "memory");
    __builtin_amdgcn_s_barrier();

    int bB = 0;
    for (int f = 0; f < TOT; ++f) {
        const int bA = f & 1;
        int f1 = f + 1; if (f1 > TOT - 1) f1 = TOT - 1;
        int f2 = f + 2; if (f2 > TOT - 1) f2 = TOT - 1;
        const int bB2 = (bB >= 1) ? (bB - 1) : 2;   // (bB+2)%3

        bf16x8 a00, a01, a10, a11, b00, b01, b10, b11, c00, c01, c10, c11;

        // Ph1 (kh0, nh0)
        a00 = rdA(bA, 0, 0); a10 = rdA(bA, 1, 0);
        a01 = rdA(bA, 0, 1); a11 = rdA(bA, 1, 1);
        b00 = rdB(bB, 0, 0); b10 = rdB(bB, 1, 0);
        b01 = rdB(bB, 0, 1); b11 = rdB(bB, 1, 1);
        stgA(f1, 0, bA ^ 1);
        PH_PRE();
        MFMA32(acc[0][0], a00, b00); MFMA32(acc[1][0], a10, b00);
        MFMA32(acc[0][1], a00, b10); MFMA32(acc[1][1], a10, b10);
        MFMA32(acc[0][0], a01, b01); MFMA32(acc[1][0], a11, b01);
        MFMA32(acc[0][1], a01, b11); MFMA32(acc[1][1], a11, b11);
        PH_POST();

        // Ph2 (kh0, nh1)
        c00 = rdB(bB, 2, 0); c10 = rdB(bB, 3, 0);
        c01 = rdB(bB, 2, 1); c11 = rdB(bB, 3, 1);
        stgA(f1, 1, bA ^ 1);
        PH_PRE();
        MFMA32(acc[0][2], a00, c00); MFMA32(acc[1][2], a10, c00);
        MFMA32(acc[0][3], a00, c10); MFMA32(acc[1][3], a10, c10);
        MFMA32(acc[0][2], a01, c01); MFMA32(acc[1][2], a11, c01);
        MFMA32(acc[0][3], a01, c11); MFMA32(acc[1][3], a11, c11);
        PH_POST();

        // Ph3 (kh1, nh0)
        a00 = rdA(bA, 0, 2); a10 = rdA(bA, 1, 2);
        a01 = rdA(bA, 0, 3); a11 = rdA(bA, 1, 3);
        b00 = rdB(bB, 0, 2); b10 = rdB(bB, 1, 2);
        b01 = rdB(bB, 0, 3); b11 = rdB(bB, 1, 3);
        stgB(f2, 0, bB2);
        PH_PRE();
        MFMA32(acc[0][0], a00, b00); MFMA32(acc[1][0], a10, b00);
        MFMA32(acc[0][1], a00, b10); MFMA32(acc[1][1], a10, b10);
        MFMA32(acc[0][0], a01, b01); MFMA32(acc[1][0], a11, b01);
        MFMA32(acc[0][1], a01, b11); MFMA32(acc[1][1], a11, b11);
        PH_POST();

        // Ph4 (kh1, nh1)
        c00 = rdB(bB, 2, 2); c10 = rdB(bB, 3, 2);
        c01 = rdB(bB, 2, 3); c11 = rdB(bB, 3, 3);
        stgB(f2, 1, bB2);
        PH_PRE();
        MFMA32(acc[0][2], a00, c00); MFMA32(acc[1][2], a10, c00);
        MFMA32(acc[0][3], a00, c10); MFMA32(acc[1][3], a10, c10);
        MFMA32(acc[0][2], a01, c01); MFMA32(acc[1][2], a11, c01);
        MFMA32(acc[0][3], a01, c11); MFMA32(acc[1][3], a11, c11);
        __builtin_amdgcn_s_setprio(0);
        __builtin_amdgcn_sched_barrier(0);
        asm volatile("s_waitcnt vmcnt(4)" ::: "memory");   // A(f+1),B(f+1) landed; B(f+2) flying
        __builtin_amdgcn_s_barrier();

        if ((f & (NTK - 1)) == NTK - 1) {
            epi(f >> NTK_LOG2, acc);
            #pragma unroll
            for (int i = 0; i < 2; ++i)
                #pragma unroll
                for (int j = 0; j < 4; ++j) acc[i][j] = (f32x16)0.f;
        }
        bB = (bB == 2) ? 0 : bB + 1;
    }
    asm volatile("s_waitcnt vmcnt(0)" ::: "memory");   // drain tail stages
}

// gates GEMM: A [16384][2048] bf16, WT [4096][2048] bf16 (gate-interleaved cols).
// grid 256 = 1 block/CU; each block chains 4 m-tiles at fixed n-panel.
__global__ __launch_bounds__(512, 2)
void gemm_gates(const unsigned short* __restrict__ A, const unsigned short* __restrict__ WT,
                const float* __restrict__ bsum,
                const float* __restrict__ c_prev, const float* __restrict__ n_prev,
                float* __restrict__ out_h, float* __restrict__ out_C, float* __restrict__ out_n,
                unsigned short* __restrict__ h_bf)
{
    __shared__ unsigned short lds[81920];   // 160 KB
    const int t = threadIdx.x;
    const int b = blockIdx.x;               // 256 blocks
    const int nb  = (b & 7) * 2 + (b >> 7);         // 0..15 ; XCD sees 2 n-panels
    const int mb0 = ((b >> 3) & 15) * 4;            // m-tiles mb0..mb0+3
    const int m0base = mb0 * 256;
    const int n0 = nb * 256;                        // c'-space

    const int lane = t & 63, wid = t >> 6;
    const int wr = wid >> 1, wc = wid & 1;
    const int l31 = lane & 31, hi5 = lane >> 5;
    const int j_out = (nb * 2 + wc) * 32 + l31;     // output column 0..1023 (fixed per lane)
    const float bz_ = bsum[j_out];
    const float bi_ = bsum[1024 + j_out];
    const float bf_ = bsum[2048 + j_out];
    const float bo_ = bsum[3072 + j_out];

    auto epi = [&](int ot, f32x16 (&acc)[2][4]) {
        #pragma unroll
        for (int mi = 0; mi < 2; ++mi) {
            const int rbase = m0base + ot * 256 + wr * 64 + mi * 32 + 4 * hi5;
            #pragma unroll
            for (int r = 0; r < 16; ++r) {
                const int row = rbase + (r & 3) + 8 * (r >> 2);
                const size_t idx = (size_t)row * 1024 + j_out;
                const float pz = acc[mi][0][r] + bz_;
                const float pi = acc[mi][1][r] + bi_;
                const float pf = acc[mi][2][r] + bf_;
                const float po = acc[mi][3][r] + bo_;
                const float zt = tanh_f(pz);
                const float it = __expf(pi);
                const float ft = sigm_f(pf);
                const float ot_ = sigm_f(po);
                const float Cv = ft * c_prev[idx] + it * zt;
                const float nv = ft * n_prev[idx] + it;
                const float hv = ot_ * tanh_f(Cv / (nv + EPSv));
                out_h[idx] = hv;
                out_C[idx] = Cv;
                out_n[idx] = nv;
                h_bf[idx] = f2bf(hv);
            }
        }
    };

    mfma32_chain<2048, 5, 4>(A, WT, m0base, n0, t, lds, epi);
}

// y GEMM: h_bf [16384][1024] @ WyT^T + by -> y [16384][1024] f32. grid 256, 1 tile/block.
__global__ __launch_bounds__(512, 2)
void gemm_y(const unsigned short* __restrict__ A, const unsigned short* __restrict__ WyT,
            const float* __restrict__ by, float* __restrict__ y)
{
    __shared__ unsigned short lds[81920];
    const int t = threadIdx.x;
    const int b = blockIdx.x;               // 256 = 64 mb x 4 nb
    const int nb = b & 3, mb = b >> 2;
    const int m0base = mb * 256, n0 = nb * 256;

    const int lane = t & 63, wid = t >> 6;
    const int wr = wid >> 1, wc = wid & 1;
    const int l31 = lane & 31, hi5 = lane >> 5;

    auto epi = [&](int ot, f32x16 (&acc)[2][4]) {
        (void)ot;
        #pragma unroll
        for (int mi = 0; mi < 2; ++mi) {
            const int rbase = m0base + wr * 64 + mi * 32 + 4 * hi5;
            #pragma unroll
            for (int nn = 0; nn < 4; ++nn) {
                const int c = n0 + wc * 128 + nn * 32 + l31;
                const float bc = by[c];
                #pragma unroll
                for (int r = 0; r < 16; ++r) {
                    const int row = rbase + (r & 3) + 8 * (r >> 2);
                    y[(size_t)row * 1024 + c] = acc[mi][nn][r] + bc;
                }
            }
        }
    };

    mfma32_chain<1024, 4, 1>(A, WyT, m0base, n0, t, lds, epi);
}

// ---------------- fallback f32 path (round-1 kernels) ----------------

constexpr int FBM = 64, FBN = 64, FBK = 16, FPAD = 4;

__global__ __launch_bounds__(256)
void fb_gates(const float* __restrict__ x, const float* __restrict__ h_prev,
              const float* __restrict__ c_prev, const float* __restrict__ n_prev,
              const float* __restrict__ Wz, const float* __restrict__ Rz,
              const float* __restrict__ Wi, const float* __restrict__ Ri,
              const float* __restrict__ Wf, const float* __restrict__ Rf,
              const float* __restrict__ Wo, const float* __restrict__ Ro,
              const float* __restrict__ bWz, const float* __restrict__ bRz, const float* __restrict__ bz,
              const float* __restrict__ bWi, const float* __restrict__ bRi, const float* __restrict__ bi,
              const float* __restrict__ bWf, const float* __restrict__ bRf, const float* __restrict__ bf_,
              const float* __restrict__ bWo, const float* __restrict__ bRo, const float* __restrict__ bo,
              float* __restrict__ out_h, float* __restrict__ out_C, float* __restrict__ out_n)
{
    __shared__ float sA[FBK][FBM + FPAD];
    __shared__ float sB[4][FBK][FBN + FPAD];
    const int t = threadIdx.x;
    const int col_blk = blockIdx.x & 15, row_blk = blockIdx.x >> 4;
    const int row0 = row_blk * FBM, col0 = col_blk * FBN;
    const int tx = t & 15, ty = t >> 4;
    float acc[4][4][4];
    #pragma unroll
    for (int g = 0; g < 4; ++g)
        for (int i = 0; i < 4; ++i)
            for (int j = 0; j < 4; ++j) acc[g][i][j] = 0.f;
    const int ar = t >> 2, ak = (t & 3) * 4, wk = t >> 4, wcc = (t & 15) * 4;
    for (int phase = 0; phase < 2; ++phase) {
        const float* Am = phase ? h_prev : x;
        const float* W0 = phase ? Rz : Wz; const float* W1 = phase ? Ri : Wi;
        const float* W2 = phase ? Rf : Wf; const float* W3 = phase ? Ro : Wo;
        for (int k0 = 0; k0 < 1024; k0 += FBK) {
            __syncthreads();
            {
                const float4 v = *(const float4*)(Am + (size_t)(row0 + ar) * 1024 + k0 + ak);
                sA[ak + 0][ar] = v.x; sA[ak + 1][ar] = v.y;
                sA[ak + 2][ar] = v.z; sA[ak + 3][ar] = v.w;
            }
            *(float4*)&sB[0][wk][wcc] = *(const float4*)(W0 + (size_t)(k0 + wk) * 1024 + col0 + wcc);
            *(float4*)&sB[1][wk][wcc] = *(const float4*)(W1 + (size_t)(k0 + wk) * 1024 + col0 + wcc);
            *(float4*)&sB[2][wk][wcc] = *(const float4*)(W2 + (size_t)(k0 + wk) * 1024 + col0 + wcc);
            *(float4*)&sB[3][wk][wcc] = *(const float4*)(W3 + (size_t)(k0 + wk) * 1024 + col0 + wcc);
            __syncthreads();
            #pragma unroll
            for (int kk = 0; kk < FBK; ++kk) {
                float a[4], bb[4][4];
                *(float4*)a = *(const float4*)&sA[kk][ty * 4];
                *(float4*)&bb[0][0] = *(const float4*)&sB[0][kk][tx * 4];
                *(float4*)&bb[1][0] = *(const float4*)&sB[1][kk][tx * 4];
                *(float4*)&bb[2][0] = *(const float4*)&sB[2][kk][tx * 4];
                *(float4*)&bb[3][0] = *(const float4*)&sB[3][kk][tx * 4];
                #pragma unroll
                for (int g = 0; g < 4; ++g)
                    for (int i = 0; i < 4; ++i)
                        for (int j = 0; j < 4; ++j)
                            acc[g][i][j] += a[i] * bb[g][j];
            }
        }
    }
    #pragma unroll
    for (int i = 0; i < 4; ++i) {
        const int r = row0 + ty * 4 + i;
        #pragma unroll
        for (int j = 0; j < 4; ++j) {
            const int c = col0 + tx * 4 + j;
            const float pz = acc[0][i][j] + bWz[c] + bRz[c] + bz[c];
            const float pi = acc[1][i][j] + bWi[c] + bRi[c] + bi[c];
            const float pf = acc[2][i][j] + bWf[c] + bRf[c] + bf_[c];
            const float po = acc[3][i][j] + bWo[c] + bRo[c] + bo[c];
            const float zt = tanhf(pz);
            const float it = expf(pi);
            const float ft = 1.f / (1.f + expf(-pf));
            const float ot = 1.f / (1.f + expf(-po));
            const size_t idx = (size_t)r * Hh + c;
            const float Cv = ft * c_prev[idx] + it * zt;
            const float nv = ft * n_prev[idx] + it;
            out_h[idx] = ot * tanhf(Cv / (nv + EPSv));
            out_C[idx] = Cv;
            out_n[idx] = nv;
        }
    }
}

__global__ __launch_bounds__(256)
void fb_ygemm(const float* __restrict__ hmat, const float* __restrict__ Wy,
              const float* __restrict__ by, float* __restrict__ y)
{
    __shared__ float sA[FBK][FBM + FPAD];
    __shared__ float sB[FBK][FBN + FPAD];
    const int t = threadIdx.x;
    const int col_blk = blockIdx.x & 15, row_blk = blockIdx.x >> 4;
    const int row0 = row_blk * FBM, col0 = col_blk * FBN;
    const int tx = t & 15, ty = t >> 4;
    float acc[4][4];
    #pragma unroll
    for (int i = 0; i < 4; ++i)
        for (int j = 0; j < 4; ++j) acc[i][j] = 0.f;
    const int ar = t >> 2, ak = (t & 3) * 4, wk = t >> 4, wcc = (t & 15) * 4;
    for (int k0 = 0; k0 < 1024; k0 += FBK) {
        __syncthreads();
        {
            const float4 v = *(const float4*)(hmat + (size_t)(row0 + ar) * 1024 + k0 + ak);
            sA[ak + 0][ar] = v.x; sA[ak + 1][ar] = v.y;
            sA[ak + 2][ar] = v.z; sA[ak + 3][ar] = v.w;
        }
        *(float4*)&sB[wk][wcc] = *(const float4*)(Wy + (size_t)(k0 + wk) * 1024 + col0 + wcc);
        __syncthreads();
        #pragma unroll
        for (int kk = 0; kk < FBK; ++kk) {
            float a[4], bb[4];
            *(float4*)a = *(const float4*)&sA[kk][ty * 4];
            *(float4*)bb = *(const float4*)&sB[kk][tx * 4];
            #pragma unroll
            for (int i = 0; i < 4; ++i)
                for (int j = 0; j < 4; ++j)
                    acc[i][j] += a[i] * bb[j];
        }
    }
    #pragma unroll
    for (int i = 0; i < 4; ++i) {
        const int r = row0 + ty * 4 + i;
        #pragma unroll
        for (int j = 0; j < 4; ++j) {
            const int c = col0 + tx * 4 + j;
            y[(size_t)r * Dd + c] = acc[i][j] + by[c];
        }
    }
}

// ---------------- launch ----------------

extern "C" void kernel_launch(void* const* d_in, const int* in_sizes, int n_in,
                              void* d_out, int out_size, void* d_ws, size_t ws_size,
                              hipStream_t stream) {
    const float* x      = (const float*)d_in[0];
    const float* h_prev = (const float*)d_in[1];
    const float* c_prev = (const float*)d_in[2];
    const float* n_prev = (const float*)d_in[3];
    const float* Wz  = (const float*)d_in[4];
    const float* bWz = (const float*)d_in[5];
    const float* Rz  = (const float*)d_in[6];
    const float* bRz = (const float*)d_in[7];
    const float* bz  = (const float*)d_in[8];
    const float* Wi  = (const float*)d_in[9];
    const float* bWi = (const float*)d_in[10];
    const float* Ri  = (const float*)d_in[11];
    const float* bRi = (const float*)d_in[12];
    const float* bi  = (const float*)d_in[13];
    const float* Wf  = (const float*)d_in[14];
    const float* bWf = (const float*)d_in[15];
    const float* Rf  = (const float*)d_in[16];
    const float* bRf = (const float*)d_in[17];
    const float* bf_ = (const float*)d_in[18];
    const float* Wo  = (const float*)d_in[19];
    const float* bWo = (const float*)d_in[20];
    const float* Ro  = (const float*)d_in[21];
    const float* bRo = (const float*)d_in[22];
    const float* bo  = (const float*)d_in[23];
    const float* Wy  = (const float*)d_in[24];
    const float* by  = (const float*)d_in[25];

    float* y     = (float*)d_out;
    float* out_h = y + (size_t)Bsz * Dd;
    float* out_C = out_h + (size_t)Bsz * Hh;
    float* out_n = out_C + (size_t)Bsz * Hh;

    // ws layout (bytes)
    const size_t OFF_A    = 0;           // 16384*2048*2 = 67108864
    const size_t OFF_WT   = 67108864;    // 4096*2048*2  = 16777216
    const size_t OFF_WYT  = 83886080;    // 1024*1024*2  = 2097152
    const size_t OFF_HBF  = 85983232;    // 16384*1024*2 = 33554432
    const size_t OFF_BS   = 119537664;   // 4*1024*4     = 16384
    const size_t WS_NEED  = 119554048;

    if (ws_size >= WS_NEED) {
        char* ws = (char*)d_ws;
        unsigned short* A_bf = (unsigned short*)(ws + OFF_A);
        unsigned short* WT   = (unsigned short*)(ws + OFF_WT);
        unsigned short* WyT  = (unsigned short*)(ws + OFF_WYT);
        unsigned short* h_bf = (unsigned short*)(ws + OFF_HBF);
        float* bsum          = (float*)(ws + OFF_BS);

        cvt_A<<<16384, 256, 0, stream>>>(x, h_prev, A_bf);
        // gates: g = 0:z 1:i 2:f 3:o ; W -> k [0,1024), R -> k [1024,2048)
        cvt_T<<<256, 256, 0, stream>>>(Wz, WT, 2048, 0,    0, 0);
        cvt_T<<<256, 256, 0, stream>>>(Rz, WT, 2048, 1024, 0, 0);
        cvt_T<<<256, 256, 0, stream>>>(Wi, WT, 2048, 0,    1, 0);
        cvt_T<<<256, 256, 0, stream>>>(Ri, WT, 2048, 1024, 1, 0);
        cvt_T<<<256, 256, 0, stream>>>(Wf, WT, 2048, 0,    2, 0);
        cvt_T<<<256, 256, 0, stream>>>(Rf, WT, 2048, 1024, 2, 0);
        cvt_T<<<256, 256, 0, stream>>>(Wo, WT, 2048, 0,    3, 0);
        cvt_T<<<256, 256, 0, stream>>>(Ro, WT, 2048, 1024, 3, 0);
        cvt_T<<<256, 256, 0, stream>>>(Wy, WyT, 1024, 0,   0, 1);
        bias_sum<<<4, 256, 0, stream>>>(bWz, bRz, bz, bWi, bRi, bi,
                                        bWf, bRf, bf_, bWo, bRo, bo, bsum);

        gemm_gates<<<256, 512, 0, stream>>>(A_bf, WT, bsum, c_prev, n_prev,
                                            out_h, out_C, out_n, h_bf);
        gemm_y<<<256, 512, 0, stream>>>(h_bf, WyT, by, y);
    } else {
        dim3 block(256);
        dim3 grid((Bsz / FBM) * (Hh / FBN));
        fb_gates<<<grid, block, 0, stream>>>(x, h_prev, c_prev, n_prev,
                                             Wz, Rz, Wi, Ri, Wf, Rf, Wo, Ro,
                                             bWz, bRz, bz, bWi, bRi, bi,
                                             bWf, bRf, bf_, bWo, bRo, bo,
                                             out_h, out_C, out_n);
        fb_ygemm<<<grid, block, 0, stream>>>(out_h, Wy, by, y);
    }
}

// Round 7
// 439.009 us; speedup vs baseline: 1.0663x; 1.0663x over previous
//
#include <hip/hip_runtime.h>
#include <math.h>
#include <stdint.h>

// sLSTM cell, B=16384, D=H=1024.
// bf16-MFMA path (needs ws >= ~114 MB):
//   cvt kernels: A=[x|h_prev] bf16 [16384][2048], WT gate-interleaved bf16 [4096][2048],
//   WyT bf16 [1024][1024], bsum f32 [4][1024].
//   gemm_gates / gemm_y: 256x256-tile BK=64 MFMA GEMM (16x16x32), A-dbuf + B-tbuf (160KB),
//   ONE barrier + ONE counted vmcnt(12) per K-tile, compiler-scheduled counted-lgkm
//   read/MFMA interleave (m97 style), precomputed LDS base offsets (zero per-read VALU),
//   T2 swizzle, chained m-tiles. Fused gate epilogue.
// Fallback (small ws): round-1 f32 vector kernels.

typedef __attribute__((ext_vector_type(8))) short bf16x8;
typedef __attribute__((ext_vector_type(4))) float f32x4;

constexpr int Bsz = 16384;
constexpr int Dd  = 1024;
constexpr int Hh  = 1024;
constexpr float EPSv = 1e-7f;

__device__ __forceinline__ unsigned short f2bf(float f) {
    union { float f; uint32_t u; } v; v.f = f;
    uint32_t u = v.u + 0x7fffu + ((v.u >> 16) & 1u);   // RNE
    return (unsigned short)(u >> 16);
}

__device__ __forceinline__ void gload16(const void* g, void* l) {
    __builtin_amdgcn_global_load_lds(
        (const __attribute__((address_space(1))) void*)g,
        (__attribute__((address_space(3))) void*)l, 16, 0, 0);
}

__device__ __forceinline__ float sigm_f(float x) { return 1.f / (1.f + __expf(-x)); }
__device__ __forceinline__ float tanh_f(float x) {   // overflow-safe fast tanh
    const float ax = fabsf(x);
    const float t = __expf(-2.f * ax);
    const float r = (1.f - t) / (1.f + t);
    return copysignf(r, x);
}

// ---------------- conversion kernels ----------------

__global__ __launch_bounds__(256)
void cvt_A(const float* __restrict__ x, const float* __restrict__ hp, unsigned short* __restrict__ A)
{
    const int idx = blockIdx.x * 256 + threadIdx.x;   // 8 elements each
    const int n = idx * 8;
    const int b = n >> 11, k = n & 2047;
    const float* s = (k < 1024) ? (x + (size_t)b * 1024 + k)
                                : (hp + (size_t)b * 1024 + (k - 1024));
    const float4 v0 = *(const float4*)s;
    const float4 v1 = *(const float4*)(s + 4);
    union { unsigned short u[8]; uint4 v; } pk;
    pk.u[0] = f2bf(v0.x); pk.u[1] = f2bf(v0.y); pk.u[2] = f2bf(v0.z); pk.u[3] = f2bf(v0.w);
    pk.u[4] = f2bf(v1.x); pk.u[5] = f2bf(v1.y); pk.u[6] = f2bf(v1.z); pk.u[7] = f2bf(v1.w);
    *(uint4*)(A + n) = pk.v;
}

// src [1024][1024] f32 (rows=k, cols=j) -> dst[c'][kbase+k] bf16.
// mode 0: c' = (j&15)|(g<<4)|((j>>4)<<6)   (gate-interleaved, 16-col granules)
// mode 1: c' = j
__global__ __launch_bounds__(256)
void cvt_T(const float* __restrict__ src, unsigned short* __restrict__ dst,
           int ldd, int kbase, int g, int mode)
{
    __shared__ float tile[64][65];
    const int t = threadIdx.x;
    const int kt = blockIdx.x & 15, jt = blockIdx.x >> 4;
    {
        const int lr = t >> 4, lc = (t & 15) * 4;
        #pragma unroll
        for (int rr = 0; rr < 64; rr += 16) {
            const float4 v = *(const float4*)(src + (size_t)(kt * 64 + rr + lr) * 1024 + jt * 64 + lc);
            tile[rr + lr][lc + 0] = v.x;
            tile[rr + lr][lc + 1] = v.y;
            tile[rr + lr][lc + 2] = v.z;
            tile[rr + lr][lc + 3] = v.w;
        }
    }
    __syncthreads();
    const int jl = t >> 2, kc = (t & 3) * 16;
    const int j = jt * 64 + jl;
    const int cp = mode ? j : ((j & 15) | (g << 4) | ((j >> 4) << 6));
    union { unsigned short u[16]; uint4 v[2]; } pk;
    #pragma unroll
    for (int q = 0; q < 16; ++q) pk.u[q] = f2bf(tile[kc + q][jl]);
    uint4* d = (uint4*)(dst + (size_t)cp * ldd + kbase + kt * 64 + kc);
    d[0] = pk.v[0];
    d[1] = pk.v[1];
}

__global__ __launch_bounds__(256)
void bias_sum(const float* bWz, const float* bRz, const float* bz,
              const float* bWi, const float* bRi, const float* bi,
              const float* bWf, const float* bRf, const float* bf_,
              const float* bWo, const float* bRo, const float* bo,
              float* __restrict__ bs)
{
    const int j = blockIdx.x * 256 + threadIdx.x;   // grid 4
    bs[j]        = bWz[j] + bRz[j] + bz[j];
    bs[1024 + j] = bWi[j] + bRi[j] + bi[j];
    bs[2048 + j] = bWf[j] + bRf[j] + bf_[j];
    bs[3072 + j] = bWo[j] + bRo[j] + bo[j];
}

// ---------------- MFMA GEMM core: 256x256 tile, BK=64, 1 bar + 1 vmcnt per K-tile ----------------
// 512 threads = 8 waves (2 wave-rows x 4 wave-cols). Per-wave output 128x64 = acc[8][4], 16x16x32.
// LDS 160KB: Abuf[2]@0 (2x32KB) + Bbuf[3]@64KB (3x32KB). Tile = [256 rows][64 k] bf16, 128B rows.
// Swizzle (T2): 16B chunk c stored at c^(row&7); staged via inverse-swizzled global source +
//   linear global_load_lds dest (rule #21). Fragment read (16 rows x 4 chunks) = 0 conflicts (R4).
// Per K-tile f: bar (WAR gate) | stage A(f+1)->A[f&1^1], B(f+2)->B[(f+2)%3] | vmcnt(12)
//   (retires A(f),B(f); leaves B(f+1),A(f+1),B(f+2) in flight — T4, never 0) |
//   24 ds_reads (base+imm, no per-read VALU) + 64 MFMA, compiler-counted lgkm interleave.

template<int LD, int NTK, int NTILES, class Epi>
__device__ void mfma_core(const unsigned short* __restrict__ Ag,
                          const unsigned short* __restrict__ Bg,
                          int m0base, int n0, int t,
                          unsigned short* lds, Epi epi)
{
    constexpr int TOT = NTK * NTILES;
    const int lane = t & 63, wid = t >> 6;
    const int wr = wid >> 2, wc = wid & 3;            // 2M x 4N wave grid
    const int cl = lane & 15, hi = lane >> 4;
    char* const L = (char*)lds;
    // read bases (bytes): row*128 + swizzled-chunk*16 ; +mf/nf*2048 imm ; ks1: ^64 ; buf: +(b<<15)
    const int rdA0 = (wr * 128 + cl) * 128 + ((hi ^ (cl & 7)) << 4);
    const int rdB0 = 65536 + (wc * 64 + cl) * 128 + ((hi ^ (cl & 7)) << 4);
    // staging: thread t -> 16B at region + t*16 (linear dest), source chunk inverse-swizzled
    const int srow = t >> 3;
    const int schk = ((t & 7) ^ (srow & 7)) * 8;      // shorts
    const int sdst = t * 16;                          // bytes

    auto stgA = [&](int f, int buf) {
        const int ot = f / NTK, kt = f % NTK;
        const unsigned short* g = Ag + (size_t)(m0base + ot * 256 + srow) * LD + kt * 64 + schk;
        char* d = L + buf * 32768 + sdst;
        gload16(g,                  d);
        gload16(g + (size_t) 64 * LD, d + 8192);
        gload16(g + (size_t)128 * LD, d + 16384);
        gload16(g + (size_t)192 * LD, d + 24576);
    };
    auto stgB = [&](int f, int buf) {
        const int kt = f % NTK;
        const unsigned short* g = Bg + (size_t)(n0 + srow) * LD + kt * 64 + schk;
        char* d = L + 65536 + buf * 32768 + sdst;
        gload16(g,                  d);
        gload16(g + (size_t) 64 * LD, d + 8192);
        gload16(g + (size_t)128 * LD, d + 16384);
        gload16(g + (size_t)192 * LD, d + 24576);
    };

    f32x4 acc[8][4];
    #pragma unroll
    for (int i = 0; i < 8; ++i)
        #pragma unroll
        for (int j = 0; j < 4; ++j) acc[i][j] = (f32x4)0.f;

    // prologue: A(0)->A0, B(0)->B0, B(1)->B1 (12 loads in flight)
    stgA(0, 0); stgB(0, 0); stgB(1, 1);

    int bA = 0, bB = 0;
    for (int f = 0; f < TOT; ++f) {
        const int f1 = (f + 1 < TOT) ? f + 1 : TOT - 1;
        const int f2 = (f + 2 < TOT) ? f + 2 : TOT - 1;
        const int bB2 = (bB >= 1) ? bB - 1 : 2;       // (bB+2)%3

        __builtin_amdgcn_s_barrier();                 // WAR: all waves done reading f-1 buffers
        stgA(f1, bA ^ 1);
        stgB(f2, bB2);
        asm volatile("s_waitcnt vmcnt(12)" ::: "memory");   // A(f),B(f) landed

        const int aof = rdA0 + (bA << 15);
        const int bof = rdB0 + (bB << 15);
        bf16x8 a[8], b[4];

        // k-sub 0
        #pragma unroll
        for (int mf = 0; mf < 8; ++mf) a[mf] = *(const bf16x8*)(L + aof + mf * 2048);
        #pragma unroll
        for (int nf = 0; nf < 4; ++nf) b[nf] = *(const bf16x8*)(L + bof + nf * 2048);
        #pragma unroll
        for (int mf = 0; mf < 8; ++mf)
            #pragma unroll
            for (int nf = 0; nf < 4; ++nf)
                acc[mf][nf] = __builtin_amdgcn_mfma_f32_16x16x32_bf16(a[mf], b[nf], acc[mf][nf], 0, 0, 0);

        // k-sub 1 (chunk ^64)
        #pragma unroll
        for (int mf = 0; mf < 8; ++mf) a[mf] = *(const bf16x8*)(L + (aof ^ 64) + mf * 2048);
        #pragma unroll
        for (int nf = 0; nf < 4; ++nf) b[nf] = *(const bf16x8*)(L + (bof ^ 64) + nf * 2048);
        #pragma unroll
        for (int mf = 0; mf < 8; ++mf)
            #pragma unroll
            for (int nf = 0; nf < 4; ++nf)
                acc[mf][nf] = __builtin_amdgcn_mfma_f32_16x16x32_bf16(a[mf], b[nf], acc[mf][nf], 0, 0, 0);

        if ((f % NTK) == NTK - 1) {
            epi(f / NTK, acc);
            #pragma unroll
            for (int i = 0; i < 8; ++i)
                #pragma unroll
                for (int j = 0; j < 4; ++j) acc[i][j] = (f32x4)0.f;
        }
        bA ^= 1;
        bB = (bB == 2) ? 0 : bB + 1;
    }
    asm volatile("s_waitcnt vmcnt(0)" ::: "memory");  // drain tail junk stages
}

// gates GEMM: A [16384][2048] bf16, WT [4096][2048] bf16 (gate-interleaved cols).
// grid 256 = 1 block/CU; each block chains 4 m-tiles at fixed n-panel.
__global__ __launch_bounds__(512, 2)
void gemm_gates(const unsigned short* __restrict__ A, const unsigned short* __restrict__ WT,
                const float* __restrict__ bsum,
                const float* __restrict__ c_prev, const float* __restrict__ n_prev,
                float* __restrict__ out_h, float* __restrict__ out_C, float* __restrict__ out_n,
                unsigned short* __restrict__ h_bf)
{
    __shared__ unsigned short lds[81920];   // 160 KB
    const int t = threadIdx.x;
    const int b = blockIdx.x;               // 256 blocks
    const int nb  = (b & 7) * 2 + (b >> 7);         // 0..15 ; each XCD holds 2 n-panels in L2
    const int mb0 = ((b >> 3) & 15) * 4;            // m-tiles mb0..mb0+3
    const int m0base = mb0 * 256;
    const int n0 = nb * 256;                        // c'-space

    const int lane = t & 63, wid = t >> 6;
    const int wr = wid >> 2, wc = wid & 3;
    const int cl = lane & 15, hi = lane >> 4;
    const int j_out = nb * 64 + wc * 16 + cl;       // output column 0..1023
    const float bz_ = bsum[j_out];
    const float bi_ = bsum[1024 + j_out];
    const float bf_ = bsum[2048 + j_out];
    const float bo_ = bsum[3072 + j_out];

    auto epi = [&](int ot, f32x4 (&acc)[8][4]) {
        #pragma unroll
        for (int mf = 0; mf < 8; ++mf) {
            const int rb = m0base + ot * 256 + wr * 128 + mf * 16 + hi * 4;
            #pragma unroll
            for (int r = 0; r < 4; ++r) {
                const size_t idx = (size_t)(rb + r) * 1024 + j_out;
                const float pz = acc[mf][0][r] + bz_;
                const float pi = acc[mf][1][r] + bi_;
                const float pf = acc[mf][2][r] + bf_;
                const float po = acc[mf][3][r] + bo_;
                const float zt = tanh_f(pz);
                const float it = __expf(pi);
                const float ft = sigm_f(pf);
                const float ot_ = sigm_f(po);
                const float Cv = ft * c_prev[idx] + it * zt;
                const float nv = ft * n_prev[idx] + it;
                const float hv = ot_ * tanh_f(Cv / (nv + EPSv));
                out_h[idx] = hv;
                out_C[idx] = Cv;
                out_n[idx] = nv;
                h_bf[idx] = f2bf(hv);
            }
        }
    };

    mfma_core<2048, 32, 4>(A, WT, m0base, n0, t, lds, epi);
}

// y GEMM: h_bf [16384][1024] @ WyT^T + by -> y [16384][1024] f32. grid 256, 1 tile/block.
__global__ __launch_bounds__(512, 2)
void gemm_y(const unsigned short* __restrict__ A, const unsigned short* __restrict__ WyT,
            const float* __restrict__ by, float* __restrict__ y)
{
    __shared__ unsigned short lds[81920];
    const int t = threadIdx.x;
    const int b = blockIdx.x;               // 256 = 64 mb x 4 nb
    const int nb = b & 3, mb = b >> 2;
    const int m0base = mb * 256, n0 = nb * 256;

    const int lane = t & 63, wid = t >> 6;
    const int wr = wid >> 2, wc = wid & 3;
    const int cl = lane & 15, hi = lane >> 4;

    auto epi = [&](int ot, f32x4 (&acc)[8][4]) {
        (void)ot;
        #pragma unroll
        for (int mf = 0; mf < 8; ++mf) {
            const int rb = m0base + wr * 128 + mf * 16 + hi * 4;
            #pragma unroll
            for (int nf = 0; nf < 4; ++nf) {
                const int c = n0 + wc * 64 + nf * 16 + cl;
                const float bc = by[c];
                #pragma unroll
                for (int r = 0; r < 4; ++r)
                    y[(size_t)(rb + r) * 1024 + c] = acc[mf][nf][r] + bc;
            }
        }
    };

    mfma_core<1024, 16, 1>(A, WyT, m0base, n0, t, lds, epi);
}

// ---------------- fallback f32 path (round-1 kernels) ----------------

constexpr int FBM = 64, FBN = 64, FBK = 16, FPAD = 4;

__global__ __launch_bounds__(256)
void fb_gates(const float* __restrict__ x, const float* __restrict__ h_prev,
              const float* __restrict__ c_prev, const float* __restrict__ n_prev,
              const float* __restrict__ Wz, const float* __restrict__ Rz,
              const float* __restrict__ Wi, const float* __restrict__ Ri,
              const float* __restrict__ Wf, const float* __restrict__ Rf,
              const float* __restrict__ Wo, const float* __restrict__ Ro,
              const float* __restrict__ bWz, const float* __restrict__ bRz, const float* __restrict__ bz,
              const float* __restrict__ bWi, const float* __restrict__ bRi, const float* __restrict__ bi,
              const float* __restrict__ bWf, const float* __restrict__ bRf, const float* __restrict__ bf_,
              const float* __restrict__ bWo, const float* __restrict__ bRo, const float* __restrict__ bo,
              float* __restrict__ out_h, float* __restrict__ out_C, float* __restrict__ out_n)
{
    __shared__ float sA[FBK][FBM + FPAD];
    __shared__ float sB[4][FBK][FBN + FPAD];
    const int t = threadIdx.x;
    const int col_blk = blockIdx.x & 15, row_blk = blockIdx.x >> 4;
    const int row0 = row_blk * FBM, col0 = col_blk * FBN;
    const int tx = t & 15, ty = t >> 4;
    float acc[4][4][4];
    #pragma unroll
    for (int g = 0; g < 4; ++g)
        for (int i = 0; i < 4; ++i)
            for (int j = 0; j < 4; ++j) acc[g][i][j] = 0.f;
    const int ar = t >> 2, ak = (t & 3) * 4, wk = t >> 4, wcc = (t & 15) * 4;
    for (int phase = 0; phase < 2; ++phase) {
        const float* Am = phase ? h_prev : x;
        const float* W0 = phase ? Rz : Wz; const float* W1 = phase ? Ri : Wi;
        const float* W2 = phase ? Rf : Wf; const float* W3 = phase ? Ro : Wo;
        for (int k0 = 0; k0 < 1024; k0 += FBK) {
            __syncthreads();
            {
                const float4 v = *(const float4*)(Am + (size_t)(row0 + ar) * 1024 + k0 + ak);
                sA[ak + 0][ar] = v.x; sA[ak + 1][ar] = v.y;
                sA[ak + 2][ar] = v.z; sA[ak + 3][ar] = v.w;
            }
            *(float4*)&sB[0][wk][wcc] = *(const float4*)(W0 + (size_t)(k0 + wk) * 1024 + col0 + wcc);
            *(float4*)&sB[1][wk][wcc] = *(const float4*)(W1 + (size_t)(k0 + wk) * 1024 + col0 + wcc);
            *(float4*)&sB[2][wk][wcc] = *(const float4*)(W2 + (size_t)(k0 + wk) * 1024 + col0 + wcc);
            *(float4*)&sB[3][wk][wcc] = *(const float4*)(W3 + (size_t)(k0 + wk) * 1024 + col0 + wcc);
            __syncthreads();
            #pragma unroll
            for (int kk = 0; kk < FBK; ++kk) {
                float a[4], bb[4][4];
                *(float4*)a = *(const float4*)&sA[kk][ty * 4];
                *(float4*)&bb[0][0] = *(const float4*)&sB[0][kk][tx * 4];
                *(float4*)&bb[1][0] = *(const float4*)&sB[1][kk][tx * 4];
                *(float4*)&bb[2][0] = *(const float4*)&sB[2][kk][tx * 4];
                *(float4*)&bb[3][0] = *(const float4*)&sB[3][kk][tx * 4];
                #pragma unroll
                for (int g = 0; g < 4; ++g)
                    for (int i = 0; i < 4; ++i)
                        for (int j = 0; j < 4; ++j)
                            acc[g][i][j] += a[i] * bb[g][j];
            }
        }
    }
    #pragma unroll
    for (int i = 0; i < 4; ++i) {
        const int r = row0 + ty * 4 + i;
        #pragma unroll
        for (int j = 0; j < 4; ++j) {
            const int c = col0 + tx * 4 + j;
            const float pz = acc[0][i][j] + bWz[c] + bRz[c] + bz[c];
            const float pi = acc[1][i][j] + bWi[c] + bRi[c] + bi[c];
            const float pf = acc[2][i][j] + bWf[c] + bRf[c] + bf_[c];
            const float po = acc[3][i][j] + bWo[c] + bRo[c] + bo[c];
            const float zt = tanhf(pz);
            const float it = expf(pi);
            const float ft = 1.f / (1.f + expf(-pf));
            const float ot = 1.f / (1.f + expf(-po));
            const size_t idx = (size_t)r * Hh + c;
            const float Cv = ft * c_prev[idx] + it * zt;
            const float nv = ft * n_prev[idx] + it;
            out_h[idx] = ot * tanhf(Cv / (nv + EPSv));
            out_C[idx] = Cv;
            out_n[idx] = nv;
        }
    }
}

__global__ __launch_bounds__(256)
void fb_ygemm(const float* __restrict__ hmat, const float* __restrict__ Wy,
              const float* __restrict__ by, float* __restrict__ y)
{
    __shared__ float sA[FBK][FBM + FPAD];
    __shared__ float sB[FBK][FBN + FPAD];
    const int t = threadIdx.x;
    const int col_blk = blockIdx.x & 15, row_blk = blockIdx.x >> 4;
    const int row0 = row_blk * FBM, col0 = col_blk * FBN;
    const int tx = t & 15, ty = t >> 4;
    float acc[4][4];
    #pragma unroll
    for (int i = 0; i < 4; ++i)
        for (int j = 0; j < 4; ++j) acc[i][j] = 0.f;
    const int ar = t >> 2, ak = (t & 3) * 4, wk = t >> 4, wcc = (t & 15) * 4;
    for (int k0 = 0; k0 < 1024; k0 += FBK) {
        __syncthreads();
        {
            const float4 v = *(const float4*)(hmat + (size_t)(row0 + ar) * 1024 + k0 + ak);
            sA[ak + 0][ar] = v.x; sA[ak + 1][ar] = v.y;
            sA[ak + 2][ar] = v.z; sA[ak + 3][ar] = v.w;
        }
        *(float4*)&sB[wk][wcc] = *(const float4*)(Wy + (size_t)(k0 + wk) * 1024 + col0 + wcc);
        __syncthreads();
        #pragma unroll
        for (int kk = 0; kk < FBK; ++kk) {
            float a[4], bb[4];
            *(float4*)a = *(const float4*)&sA[kk][ty * 4];
            *(float4*)bb = *(const float4*)&sB[kk][tx * 4];
            #pragma unroll
            for (int i = 0; i < 4; ++i)
                for (int j = 0; j < 4; ++j)
                    acc[i][j] += a[i] * bb[j];
        }
    }
    #pragma unroll
    for (int i = 0; i < 4; ++i) {
        const int r = row0 + ty * 4 + i;
        #pragma unroll
        for (int j = 0; j < 4; ++j) {
            const int c = col0 + tx * 4 + j;
            y[(size_t)r * Dd + c] = acc[i][j] + by[c];
        }
    }
}

// ---------------- launch ----------------

extern "C" void kernel_launch(void* const* d_in, const int* in_sizes, int n_in,
                              void* d_out, int out_size, void* d_ws, size_t ws_size,
                              hipStream_t stream) {
    const float* x      = (const float*)d_in[0];
    const float* h_prev = (const float*)d_in[1];
    const float* c_prev = (const float*)d_in[2];
    const float* n_prev = (const float*)d_in[3];
    const float* Wz  = (const float*)d_in[4];
    const float* bWz = (const float*)d_in[5];
    const float* Rz  = (const float*)d_in[6];
    const float* bRz = (const float*)d_in[7];
    const float* bz  = (const float*)d_in[8];
    const float* Wi  = (const float*)d_in[9];
    const float* bWi = (const float*)d_in[10];
    const float* Ri  = (const float*)d_in[11];
    const float* bRi = (const float*)d_in[12];
    const float* bi  = (const float*)d_in[13];
    const float* Wf  = (const float*)d_in[14];
    const float* bWf = (const float*)d_in[15];
    const float* Rf  = (const float*)d_in[16];
    const float* bRf = (const float*)d_in[17];
    const float* bf_ = (const float*)d_in[18];
    const float* Wo  = (const float*)d_in[19];
    const float* bWo = (const float*)d_in[20];
    const float* Ro  = (const float*)d_in[21];
    const float* bRo = (const float*)d_in[22];
    const float* bo  = (const float*)d_in[23];
    const float* Wy  = (const float*)d_in[24];
    const float* by  = (const float*)d_in[25];

    float* y     = (float*)d_out;
    float* out_h = y + (size_t)Bsz * Dd;
    float* out_C = out_h + (size_t)Bsz * Hh;
    float* out_n = out_C + (size_t)Bsz * Hh;

    // ws layout (bytes)
    const size_t OFF_A    = 0;           // 16384*2048*2 = 67108864
    const size_t OFF_WT   = 67108864;    // 4096*2048*2  = 16777216
    const size_t OFF_WYT  = 83886080;    // 1024*1024*2  = 2097152
    const size_t OFF_HBF  = 85983232;    // 16384*1024*2 = 33554432
    const size_t OFF_BS   = 119537664;   // 4*1024*4     = 16384
    const size_t WS_NEED  = 119554048;

    if (ws_size >= WS_NEED) {
        char* ws = (char*)d_ws;
        unsigned short* A_bf = (unsigned short*)(ws + OFF_A);
        unsigned short* WT   = (unsigned short*)(ws + OFF_WT);
        unsigned short* WyT  = (unsigned short*)(ws + OFF_WYT);
        unsigned short* h_bf = (unsigned short*)(ws + OFF_HBF);
        float* bsum          = (float*)(ws + OFF_BS);

        cvt_A<<<16384, 256, 0, stream>>>(x, h_prev, A_bf);
        // gates: g = 0:z 1:i 2:f 3:o ; W -> k [0,1024), R -> k [1024,2048)
        cvt_T<<<256, 256, 0, stream>>>(Wz, WT, 2048, 0,    0, 0);
        cvt_T<<<256, 256, 0, stream>>>(Rz, WT, 2048, 1024, 0, 0);
        cvt_T<<<256, 256, 0, stream>>>(Wi, WT, 2048, 0,    1, 0);
        cvt_T<<<256, 256, 0, stream>>>(Ri, WT, 2048, 1024, 1, 0);
        cvt_T<<<256, 256, 0, stream>>>(Wf, WT, 2048, 0,    2, 0);
        cvt_T<<<256, 256, 0, stream>>>(Rf, WT, 2048, 1024, 2, 0);
        cvt_T<<<256, 256, 0, stream>>>(Wo, WT, 2048, 0,    3, 0);
        cvt_T<<<256, 256, 0, stream>>>(Ro, WT, 2048, 1024, 3, 0);
        cvt_T<<<256, 256, 0, stream>>>(Wy, WyT, 1024, 0,   0, 1);
        bias_sum<<<4, 256, 0, stream>>>(bWz, bRz, bz, bWi, bRi, bi,
                                        bWf, bRf, bf_, bWo, bRo, bo, bsum);

        gemm_gates<<<256, 512, 0, stream>>>(A_bf, WT, bsum, c_prev, n_prev,
                                            out_h, out_C, out_n, h_bf);
        gemm_y<<<256, 512, 0, stream>>>(h_bf, WyT, by, y);
    } else {
        dim3 block(256);
        dim3 grid((Bsz / FBM) * (Hh / FBN));
        fb_gates<<<grid, block, 0, stream>>>(x, h_prev, c_prev, n_prev,
                                             Wz, Rz, Wi, Ri, Wf, Rf, Wo, Ro,
                                             bWz, bRz, bz, bWi, bRi, bi,
                                             bWf, bRf, bf_, bWo, bRo, bo,
                                             out_h, out_C, out_n);
        fb_ygemm<<<grid, block, 0, stream>>>(out_h, Wy, by, y);
    }
}

// Round 8
// 425.600 us; speedup vs baseline: 1.0999x; 1.0315x over previous
//
#include <hip/hip_runtime.h>
#include <math.h>
#include <stdint.h>

// sLSTM cell, B=16384, D=H=1024.
// bf16-MFMA path (needs ws >= ~114 MB):
//   cvt_A: A=[x|h_prev] bf16 [16384][2048]; cvt_W (merged): WT gate-interleaved bf16
//   [4096][2048], WyT bf16 [1024][1024], bsum f32 [4][1024].
//   gemm_gates / gemm_y: 256x256-tile BK=64 MFMA GEMM (16x16x32), A-dbuf + B-tbuf (160KB),
//   ONE barrier + counted vmcnt(4) per K-tile, inline-asm ds_reads with counted lgkm waits
//   (ks1 fragment drain hidden under ks0 MFMA cluster), T2 swizzle, chained m-tiles.
// Fallback (small ws): round-1 f32 vector kernels.

typedef __attribute__((ext_vector_type(8))) short bf16x8;
typedef __attribute__((ext_vector_type(4))) float f32x4;

constexpr int Bsz = 16384;
constexpr int Dd  = 1024;
constexpr int Hh  = 1024;
constexpr float EPSv = 1e-7f;

__device__ __forceinline__ unsigned short f2bf(float f) {
    union { float f; uint32_t u; } v; v.f = f;
    uint32_t u = v.u + 0x7fffu + ((v.u >> 16) & 1u);   // RNE
    return (unsigned short)(u >> 16);
}

__device__ __forceinline__ void gload16(const void* g, void* l) {
    __builtin_amdgcn_global_load_lds(
        (const __attribute__((address_space(1))) void*)g,
        (__attribute__((address_space(3))) void*)l, 16, 0, 0);
}

__device__ __forceinline__ float sigm_f(float x) { return 1.f / (1.f + __expf(-x)); }
__device__ __forceinline__ float tanh_f(float x) {   // overflow-safe fast tanh
    const float ax = fabsf(x);
    const float t = __expf(-2.f * ax);
    const float r = (1.f - t) / (1.f + t);
    return copysignf(r, x);
}

// inline-asm LDS read: explicit issue order + counted lgkm discipline (rule #18)
#define DSR(d, a, o) asm volatile("ds_read_b128 %0, %1 offset:" o : "=v"(d) : "v"(a) : "memory")

// ---------------- conversion kernels ----------------

__global__ __launch_bounds__(256)
void cvt_A(const float* __restrict__ x, const float* __restrict__ hp, unsigned short* __restrict__ A)
{
    const int idx = blockIdx.x * 256 + threadIdx.x;   // 8 elements each
    const int n = idx * 8;
    const int b = n >> 11, k = n & 2047;
    const float* s = (k < 1024) ? (x + (size_t)b * 1024 + k)
                                : (hp + (size_t)b * 1024 + (k - 1024));
    const float4 v0 = *(const float4*)s;
    const float4 v1 = *(const float4*)(s + 4);
    union { unsigned short u[8]; uint4 v; } pk;
    pk.u[0] = f2bf(v0.x); pk.u[1] = f2bf(v0.y); pk.u[2] = f2bf(v0.z); pk.u[3] = f2bf(v0.w);
    pk.u[4] = f2bf(v1.x); pk.u[5] = f2bf(v1.y); pk.u[6] = f2bf(v1.z); pk.u[7] = f2bf(v1.w);
    *(uint4*)(A + n) = pk.v;
}

// Merged weight-transpose + bias-sum kernel. grid 2308:
//   blocks 0..2303: id = b>>8 selects {Wz,Rz,Wi,Ri,Wf,Rf,Wo,Ro,Wy}; 256 sub-blocks each.
//   blocks 2304..2307: bias sums.
// W/R -> WT[c'][kbase+k], c' = (j&15)|(g<<4)|((j>>4)<<6); Wy -> WyT[j][k].
struct CvtArgs {
    const float* src[9];
    const float* bptr[12];
    unsigned short* wt;
    unsigned short* wyt;
    float* bs;
};

__global__ __launch_bounds__(256)
void cvt_W(CvtArgs P)
{
    __shared__ float tile[64][65];
    const int bid = blockIdx.x;
    const int t = threadIdx.x;
    if (bid >= 2304) {
        const int j = (bid - 2304) * 256 + t;
        P.bs[j]        = P.bptr[0][j] + P.bptr[1][j]  + P.bptr[2][j];
        P.bs[1024 + j] = P.bptr[3][j] + P.bptr[4][j]  + P.bptr[5][j];
        P.bs[2048 + j] = P.bptr[6][j] + P.bptr[7][j]  + P.bptr[8][j];
        P.bs[3072 + j] = P.bptr[9][j] + P.bptr[10][j] + P.bptr[11][j];
        return;
    }
    const int id = bid >> 8, sub = bid & 255;
    const float* __restrict__ src = P.src[id];
    const int kt = sub & 15, jt = sub >> 4;
    {
        const int lr = t >> 4, lc = (t & 15) * 4;
        #pragma unroll
        for (int rr = 0; rr < 64; rr += 16) {
            const float4 v = *(const float4*)(src + (size_t)(kt * 64 + rr + lr) * 1024 + jt * 64 + lc);
            tile[rr + lr][lc + 0] = v.x;
            tile[rr + lr][lc + 1] = v.y;
            tile[rr + lr][lc + 2] = v.z;
            tile[rr + lr][lc + 3] = v.w;
        }
    }
    __syncthreads();
    const int jl = t >> 2, kc = (t & 3) * 16;
    const int j = jt * 64 + jl;
    union { unsigned short u[16]; uint4 v[2]; } pk;
    #pragma unroll
    for (int q = 0; q < 16; ++q) pk.u[q] = f2bf(tile[kc + q][jl]);
    uint4* d;
    if (id == 8) {
        d = (uint4*)(P.wyt + (size_t)j * 1024 + kt * 64 + kc);
    } else {
        const int g = id >> 1, kbase = (id & 1) ? 1024 : 0;
        const int cp = (j & 15) | (g << 4) | ((j >> 4) << 6);
        d = (uint4*)(P.wt + (size_t)cp * 2048 + kbase + kt * 64 + kc);
    }
    d[0] = pk.v[0];
    d[1] = pk.v[1];
}

// ---------------- MFMA GEMM core ----------------
// 512 threads = 8 waves (2 wave-rows x 4 wave-cols). Per-wave output 128x64 = acc[8][4], 16x16x32.
// LDS 160KB: Abuf[2]@0 (2x32KB) + Bbuf[3]@64KB (3x32KB). Tile = [256 rows][64 k] bf16, 128B rows.
// Swizzle (T2): 16B chunk c stored at c^(row&7); staged via inverse-swizzled global source +
//   linear global_load_lds dest (rule #21). Fragment read (16 rows x 4 chunks) = 0 conflicts.
// Per K-tile f:
//   vmcnt(4)  — A(f),B(f) retired (everyone's, once past the barrier)  [T4: never 0]
//   s_barrier — WAR gate for staging + RAW visibility of A(f),B(f)
//   stage A(f+1)->A[bA^1], B(f+2)->B[(bB+2)%3]   (8 gloads; B(f+1) stays in flight)
//   20 asm ds_read (a0[8],b0[4],a1[8]) ; lgkmcnt(8)+SB0 -> 32 MFMA ks0 (a1 drains underneath)
//   4 asm ds_read (b1) ; lgkmcnt(0)+SB0 -> 32 MFMA ks1

template<int LD, int NTK, int NTILES, class Epi>
__device__ void mfma_core(const unsigned short* __restrict__ Ag,
                          const unsigned short* __restrict__ Bg,
                          int m0base, int n0, int t,
                          unsigned short* lds, Epi epi)
{
    constexpr int TOT = NTK * NTILES;
    const int lane = t & 63, wid = t >> 6;
    const int wr = wid >> 2, wc = wid & 3;            // 2M x 4N wave grid
    const int cl = lane & 15, hi = lane >> 4;
    const int Lb = (int)(size_t)(__attribute__((address_space(3))) unsigned short*)lds;
    const int rdA0 = Lb + (wr * 128 + cl) * 128 + ((hi ^ (cl & 7)) << 4);
    const int rdB0 = Lb + 65536 + (wc * 64 + cl) * 128 + ((hi ^ (cl & 7)) << 4);
    const int srow = t >> 3;
    const int schk = ((t & 7) ^ (srow & 7)) * 8;      // shorts
    const int sdst = t * 16;                          // bytes
    char* const L = (char*)lds;

    auto stgA = [&](int f, int buf) {
        const int ot = f / NTK, kt = f % NTK;
        const unsigned short* g = Ag + (size_t)(m0base + ot * 256 + srow) * LD + kt * 64 + schk;
        char* d = L + buf * 32768 + sdst;
        gload16(g,                  d);
        gload16(g + (size_t) 64 * LD, d + 8192);
        gload16(g + (size_t)128 * LD, d + 16384);
        gload16(g + (size_t)192 * LD, d + 24576);
    };
    auto stgB = [&](int f, int buf) {
        const int kt = f % NTK;
        const unsigned short* g = Bg + (size_t)(n0 + srow) * LD + kt * 64 + schk;
        char* d = L + 65536 + buf * 32768 + sdst;
        gload16(g,                  d);
        gload16(g + (size_t) 64 * LD, d + 8192);
        gload16(g + (size_t)128 * LD, d + 16384);
        gload16(g + (size_t)192 * LD, d + 24576);
    };

    f32x4 acc[8][4];
    #pragma unroll
    for (int i = 0; i < 8; ++i)
        #pragma unroll
        for (int j = 0; j < 4; ++j) acc[i][j] = (f32x4)0.f;

    // prologue: A(0)->A0, B(0)->B0, B(1)->B1 (12 loads in flight)
    stgA(0, 0); stgB(0, 0); stgB(1, 1);

    int bA = 0, bB = 0;
    for (int f = 0; f < TOT; ++f) {
        const int f1 = (f + 1 < TOT) ? f + 1 : TOT - 1;
        const int f2 = (f + 2 < TOT) ? f + 2 : TOT - 1;
        const int bB2 = (bB >= 1) ? bB - 1 : 2;       // (bB+2)%3

        asm volatile("s_waitcnt vmcnt(4)" ::: "memory");   // A(f),B(f) retired; B(f+1) flying
        __builtin_amdgcn_s_barrier();                      // WAR + RAW gate
        stgA(f1, bA ^ 1);
        stgB(f2, bB2);

        const int aof  = rdA0 + (bA << 15);
        const int bof  = rdB0 + (bB << 15);
        const int aof1 = aof ^ 64;
        const int bof1 = bof ^ 64;
        bf16x8 a0[8], b0[4], a1[8], b1[4];

        DSR(a0[0], aof, "0");     DSR(a0[1], aof, "2048");
        DSR(a0[2], aof, "4096");  DSR(a0[3], aof, "6144");
        DSR(a0[4], aof, "8192");  DSR(a0[5], aof, "10240");
        DSR(a0[6], aof, "12288"); DSR(a0[7], aof, "14336");
        DSR(b0[0], bof, "0");     DSR(b0[1], bof, "2048");
        DSR(b0[2], bof, "4096");  DSR(b0[3], bof, "6144");
        DSR(a1[0], aof1, "0");     DSR(a1[1], aof1, "2048");
        DSR(a1[2], aof1, "4096");  DSR(a1[3], aof1, "6144");
        DSR(a1[4], aof1, "8192");  DSR(a1[5], aof1, "10240");
        DSR(a1[6], aof1, "12288"); DSR(a1[7], aof1, "14336");

        asm volatile("s_waitcnt lgkmcnt(8)" ::: "memory");  // a0,b0 ready; a1 still draining
        __builtin_amdgcn_sched_barrier(0);
        __builtin_amdgcn_s_setprio(1);
        #pragma unroll
        for (int mf = 0; mf < 8; ++mf)
            #pragma unroll
            for (int nf = 0; nf < 4; ++nf)
                acc[mf][nf] = __builtin_amdgcn_mfma_f32_16x16x32_bf16(a0[mf], b0[nf], acc[mf][nf], 0, 0, 0);

        DSR(b1[0], bof1, "0");    DSR(b1[1], bof1, "2048");
        DSR(b1[2], bof1, "4096"); DSR(b1[3], bof1, "6144");

        asm volatile("s_waitcnt lgkmcnt(0)" ::: "memory");  // a1,b1 ready
        __builtin_amdgcn_sched_barrier(0);
        #pragma unroll
        for (int mf = 0; mf < 8; ++mf)
            #pragma unroll
            for (int nf = 0; nf < 4; ++nf)
                acc[mf][nf] = __builtin_amdgcn_mfma_f32_16x16x32_bf16(a1[mf], b1[nf], acc[mf][nf], 0, 0, 0);
        __builtin_amdgcn_s_setprio(0);

        if ((f % NTK) == NTK - 1) {
            epi(f / NTK, acc);
            #pragma unroll
            for (int i = 0; i < 8; ++i)
                #pragma unroll
                for (int j = 0; j < 4; ++j) acc[i][j] = (f32x4)0.f;
        }
        bA ^= 1;
        bB = (bB == 2) ? 0 : bB + 1;
    }
    asm volatile("s_waitcnt vmcnt(0)" ::: "memory");  // drain tail junk stages
}

// gates GEMM: A [16384][2048] bf16, WT [4096][2048] bf16 (gate-interleaved cols).
// grid 256 = 1 block/CU; each block chains 4 m-tiles at fixed n-panel.
__global__ __launch_bounds__(512, 2)
void gemm_gates(const unsigned short* __restrict__ A, const unsigned short* __restrict__ WT,
                const float* __restrict__ bsum,
                const float* __restrict__ c_prev, const float* __restrict__ n_prev,
                float* __restrict__ out_h, float* __restrict__ out_C, float* __restrict__ out_n,
                unsigned short* __restrict__ h_bf)
{
    __shared__ unsigned short lds[81920];   // 160 KB
    const int t = threadIdx.x;
    const int b = blockIdx.x;               // 256 blocks
    const int nb  = (b & 7) * 2 + (b >> 7);         // 0..15 ; each XCD holds 2 n-panels in L2
    const int mb0 = ((b >> 3) & 15) * 4;            // m-tiles mb0..mb0+3
    const int m0base = mb0 * 256;
    const int n0 = nb * 256;                        // c'-space

    const int lane = t & 63, wid = t >> 6;
    const int wr = wid >> 2, wc = wid & 3;
    const int cl = lane & 15, hi = lane >> 4;
    const int j_out = nb * 64 + wc * 16 + cl;       // output column 0..1023
    const float bz_ = bsum[j_out];
    const float bi_ = bsum[1024 + j_out];
    const float bf_ = bsum[2048 + j_out];
    const float bo_ = bsum[3072 + j_out];

    auto epi = [&](int ot, f32x4 (&acc)[8][4]) {
        #pragma unroll
        for (int mf = 0; mf < 8; ++mf) {
            const int rb = m0base + ot * 256 + wr * 128 + mf * 16 + hi * 4;
            #pragma unroll
            for (int r = 0; r < 4; ++r) {
                const size_t idx = (size_t)(rb + r) * 1024 + j_out;
                const float pz = acc[mf][0][r] + bz_;
                const float pi = acc[mf][1][r] + bi_;
                const float pf = acc[mf][2][r] + bf_;
                const float po = acc[mf][3][r] + bo_;
                const float zt = tanh_f(pz);
                const float it = __expf(pi);
                const float ft = sigm_f(pf);
                const float ot_ = sigm_f(po);
                const float Cv = ft * c_prev[idx] + it * zt;
                const float nv = ft * n_prev[idx] + it;
                const float hv = ot_ * tanh_f(Cv / (nv + EPSv));
                out_h[idx] = hv;
                out_C[idx] = Cv;
                out_n[idx] = nv;
                h_bf[idx] = f2bf(hv);
            }
        }
    };

    mfma_core<2048, 32, 4>(A, WT, m0base, n0, t, lds, epi);
}

// y GEMM: h_bf [16384][1024] @ WyT^T + by -> y [16384][1024] f32. grid 256, 1 tile/block.
__global__ __launch_bounds__(512, 2)
void gemm_y(const unsigned short* __restrict__ A, const unsigned short* __restrict__ WyT,
            const float* __restrict__ by, float* __restrict__ y)
{
    __shared__ unsigned short lds[81920];
    const int t = threadIdx.x;
    const int b = blockIdx.x;               // 256 = 64 mb x 4 nb
    const int nb = b & 3, mb = b >> 2;
    const int m0base = mb * 256, n0 = nb * 256;

    const int lane = t & 63, wid = t >> 6;
    const int wr = wid >> 2, wc = wid & 3;
    const int cl = lane & 15, hi = lane >> 4;

    auto epi = [&](int ot, f32x4 (&acc)[8][4]) {
        (void)ot;
        #pragma unroll
        for (int mf = 0; mf < 8; ++mf) {
            const int rb = m0base + wr * 128 + mf * 16 + hi * 4;
            #pragma unroll
            for (int nf = 0; nf < 4; ++nf) {
                const int c = n0 + wc * 64 + nf * 16 + cl;
                const float bc = by[c];
                #pragma unroll
                for (int r = 0; r < 4; ++r)
                    y[(size_t)(rb + r) * 1024 + c] = acc[mf][nf][r] + bc;
            }
        }
    };

    mfma_core<1024, 16, 1>(A, WyT, m0base, n0, t, lds, epi);
}

// ---------------- fallback f32 path (round-1 kernels) ----------------

constexpr int FBM = 64, FBN = 64, FBK = 16, FPAD = 4;

__global__ __launch_bounds__(256)
void fb_gates(const float* __restrict__ x, const float* __restrict__ h_prev,
              const float* __restrict__ c_prev, const float* __restrict__ n_prev,
              const float* __restrict__ Wz, const float* __restrict__ Rz,
              const float* __restrict__ Wi, const float* __restrict__ Ri,
              const float* __restrict__ Wf, const float* __restrict__ Rf,
              const float* __restrict__ Wo, const float* __restrict__ Ro,
              const float* __restrict__ bWz, const float* __restrict__ bRz, const float* __restrict__ bz,
              const float* __restrict__ bWi, const float* __restrict__ bRi, const float* __restrict__ bi,
              const float* __restrict__ bWf, const float* __restrict__ bRf, const float* __restrict__ bf_,
              const float* __restrict__ bWo, const float* __restrict__ bRo, const float* __restrict__ bo,
              float* __restrict__ out_h, float* __restrict__ out_C, float* __restrict__ out_n)
{
    __shared__ float sA[FBK][FBM + FPAD];
    __shared__ float sB[4][FBK][FBN + FPAD];
    const int t = threadIdx.x;
    const int col_blk = blockIdx.x & 15, row_blk = blockIdx.x >> 4;
    const int row0 = row_blk * FBM, col0 = col_blk * FBN;
    const int tx = t & 15, ty = t >> 4;
    float acc[4][4][4];
    #pragma unroll
    for (int g = 0; g < 4; ++g)
        for (int i = 0; i < 4; ++i)
            for (int j = 0; j < 4; ++j) acc[g][i][j] = 0.f;
    const int ar = t >> 2, ak = (t & 3) * 4, wk = t >> 4, wcc = (t & 15) * 4;
    for (int phase = 0; phase < 2; ++phase) {
        const float* Am = phase ? h_prev : x;
        const float* W0 = phase ? Rz : Wz; const float* W1 = phase ? Ri : Wi;
        const float* W2 = phase ? Rf : Wf; const float* W3 = phase ? Ro : Wo;
        for (int k0 = 0; k0 < 1024; k0 += FBK) {
            __syncthreads();
            {
                const float4 v = *(const float4*)(Am + (size_t)(row0 + ar) * 1024 + k0 + ak);
                sA[ak + 0][ar] = v.x; sA[ak + 1][ar] = v.y;
                sA[ak + 2][ar] = v.z; sA[ak + 3][ar] = v.w;
            }
            *(float4*)&sB[0][wk][wcc] = *(const float4*)(W0 + (size_t)(k0 + wk) * 1024 + col0 + wcc);
            *(float4*)&sB[1][wk][wcc] = *(const float4*)(W1 + (size_t)(k0 + wk) * 1024 + col0 + wcc);
            *(float4*)&sB[2][wk][wcc] = *(const float4*)(W2 + (size_t)(k0 + wk) * 1024 + col0 + wcc);
            *(float4*)&sB[3][wk][wcc] = *(const float4*)(W3 + (size_t)(k0 + wk) * 1024 + col0 + wcc);
            __syncthreads();
            #pragma unroll
            for (int kk = 0; kk < FBK; ++kk) {
                float a[4], bb[4][4];
                *(float4*)a = *(const float4*)&sA[kk][ty * 4];
                *(float4*)&bb[0][0] = *(const float4*)&sB[0][kk][tx * 4];
                *(float4*)&bb[1][0] = *(const float4*)&sB[1][kk][tx * 4];
                *(float4*)&bb[2][0] = *(const float4*)&sB[2][kk][tx * 4];
                *(float4*)&bb[3][0] = *(const float4*)&sB[3][kk][tx * 4];
                #pragma unroll
                for (int g = 0; g < 4; ++g)
                    for (int i = 0; i < 4; ++i)
                        for (int j = 0; j < 4; ++j)
                            acc[g][i][j] += a[i] * bb[g][j];
            }
        }
    }
    #pragma unroll
    for (int i = 0; i < 4; ++i) {
        const int r = row0 + ty * 4 + i;
        #pragma unroll
        for (int j = 0; j < 4; ++j) {
            const int c = col0 + tx * 4 + j;
            const float pz = acc[0][i][j] + bWz[c] + bRz[c] + bz[c];
            const float pi = acc[1][i][j] + bWi[c] + bRi[c] + bi[c];
            const float pf = acc[2][i][j] + bWf[c] + bRf[c] + bf_[c];
            const float po = acc[3][i][j] + bWo[c] + bRo[c] + bo[c];
            const float zt = tanhf(pz);
            const float it = expf(pi);
            const float ft = 1.f / (1.f + expf(-pf));
            const float ot = 1.f / (1.f + expf(-po));
            const size_t idx = (size_t)r * Hh + c;
            const float Cv = ft * c_prev[idx] + it * zt;
            const float nv = ft * n_prev[idx] + it;
            out_h[idx] = ot * tanhf(Cv / (nv + EPSv));
            out_C[idx] = Cv;
            out_n[idx] = nv;
        }
    }
}

__global__ __launch_bounds__(256)
void fb_ygemm(const float* __restrict__ hmat, const float* __restrict__ Wy,
              const float* __restrict__ by, float* __restrict__ y)
{
    __shared__ float sA[FBK][FBM + FPAD];
    __shared__ float sB[FBK][FBN + FPAD];
    const int t = threadIdx.x;
    const int col_blk = blockIdx.x & 15, row_blk = blockIdx.x >> 4;
    const int row0 = row_blk * FBM, col0 = col_blk * FBN;
    const int tx = t & 15, ty = t >> 4;
    float acc[4][4];
    #pragma unroll
    for (int i = 0; i < 4; ++i)
        for (int j = 0; j < 4; ++j) acc[i][j] = 0.f;
    const int ar = t >> 2, ak = (t & 3) * 4, wk = t >> 4, wcc = (t & 15) * 4;
    for (int k0 = 0; k0 < 1024; k0 += FBK) {
        __syncthreads();
        {
            const float4 v = *(const float4*)(hmat + (size_t)(row0 + ar) * 1024 + k0 + ak);
            sA[ak + 0][ar] = v.x; sA[ak + 1][ar] = v.y;
            sA[ak + 2][ar] = v.z; sA[ak + 3][ar] = v.w;
        }
        *(float4*)&sB[wk][wcc] = *(const float4*)(Wy + (size_t)(k0 + wk) * 1024 + col0 + wcc);
        __syncthreads();
        #pragma unroll
        for (int kk = 0; kk < FBK; ++kk) {
            float a[4], bb[4];
            *(float4*)a = *(const float4*)&sA[kk][ty * 4];
            *(float4*)bb = *(const float4*)&sB[kk][tx * 4];
            #pragma unroll
            for (int i = 0; i < 4; ++i)
                for (int j = 0; j < 4; ++j)
                    acc[i][j] += a[i] * bb[j];
        }
    }
    #pragma unroll
    for (int i = 0; i < 4; ++i) {
        const int r = row0 + ty * 4 + i;
        #pragma unroll
        for (int j = 0; j < 4; ++j) {
            const int c = col0 + tx * 4 + j;
            y[(size_t)r * Dd + c] = acc[i][j] + by[c];
        }
    }
}

// ---------------- launch ----------------

extern "C" void kernel_launch(void* const* d_in, const int* in_sizes, int n_in,
                              void* d_out, int out_size, void* d_ws, size_t ws_size,
                              hipStream_t stream) {
    const float* x      = (const float*)d_in[0];
    const float* h_prev = (const float*)d_in[1];
    const float* c_prev = (const float*)d_in[2];
    const float* n_prev = (const float*)d_in[3];
    const float* Wz  = (const float*)d_in[4];
    const float* bWz = (const float*)d_in[5];
    const float* Rz  = (const float*)d_in[6];
    const float* bRz = (const float*)d_in[7];
    const float* bz  = (const float*)d_in[8];
    const float* Wi  = (const float*)d_in[9];
    const float* bWi = (const float*)d_in[10];
    const float* Ri  = (const float*)d_in[11];
    const float* bRi = (const float*)d_in[12];
    const float* bi  = (const float*)d_in[13];
    const float* Wf  = (const float*)d_in[14];
    const float* bWf = (const float*)d_in[15];
    const float* Rf  = (const float*)d_in[16];
    const float* bRf = (const float*)d_in[17];
    const float* bf_ = (const float*)d_in[18];
    const float* Wo  = (const float*)d_in[19];
    const float* bWo = (const float*)d_in[20];
    const float* Ro  = (const float*)d_in[21];
    const float* bRo = (const float*)d_in[22];
    const float* bo  = (const float*)d_in[23];
    const float* Wy  = (const float*)d_in[24];
    const float* by  = (const float*)d_in[25];

    float* y     = (float*)d_out;
    float* out_h = y + (size_t)Bsz * Dd;
    float* out_C = out_h + (size_t)Bsz * Hh;
    float* out_n = out_C + (size_t)Bsz * Hh;

    // ws layout (bytes)
    const size_t OFF_A    = 0;           // 16384*2048*2 = 67108864
    const size_t OFF_WT   = 67108864;    // 4096*2048*2  = 16777216
    const size_t OFF_WYT  = 83886080;    // 1024*1024*2  = 2097152
    const size_t OFF_HBF  = 85983232;    // 16384*1024*2 = 33554432
    const size_t OFF_BS   = 119537664;   // 4*1024*4     = 16384
    const size_t WS_NEED  = 119554048;

    if (ws_size >= WS_NEED) {
        char* ws = (char*)d_ws;
        unsigned short* A_bf = (unsigned short*)(ws + OFF_A);
        unsigned short* WT   = (unsigned short*)(ws + OFF_WT);
        unsigned short* WyT  = (unsigned short*)(ws + OFF_WYT);
        unsigned short* h_bf = (unsigned short*)(ws + OFF_HBF);
        float* bsum          = (float*)(ws + OFF_BS);

        cvt_A<<<16384, 256, 0, stream>>>(x, h_prev, A_bf);

        CvtArgs P;
        P.src[0] = Wz; P.src[1] = Rz; P.src[2] = Wi; P.src[3] = Ri;
        P.src[4] = Wf; P.src[5] = Rf; P.src[6] = Wo; P.src[7] = Ro; P.src[8] = Wy;
        P.bptr[0] = bWz; P.bptr[1] = bRz; P.bptr[2]  = bz;
        P.bptr[3] = bWi; P.bptr[4] = bRi; P.bptr[5]  = bi;
        P.bptr[6] = bWf; P.bptr[7] = bRf; P.bptr[8]  = bf_;
        P.bptr[9] = bWo; P.bptr[10] = bRo; P.bptr[11] = bo;
        P.wt = WT; P.wyt = WyT; P.bs = bsum;
        cvt_W<<<2308, 256, 0, stream>>>(P);

        gemm_gates<<<256, 512, 0, stream>>>(A_bf, WT, bsum, c_prev, n_prev,
                                            out_h, out_C, out_n, h_bf);
        gemm_y<<<256, 512, 0, stream>>>(h_bf, WyT, by, y);
    } else {
        dim3 block(256);
        dim3 grid((Bsz / FBM) * (Hh / FBN));
        fb_gates<<<grid, block, 0, stream>>>(x, h_prev, c_prev, n_prev,
                                             Wz, Rz, Wi, Ri, Wf, Rf, Wo, Ro,
                                             bWz, bRz, bz, bWi, bRi, bi,
                                             bWf, bRf, bf_, bWo, bRo, bo,
                                             out_h, out_C, out_n);
        fb_ygemm<<<grid, block, 0, stream>>>(out_h, Wy, by, y);
    }
}